// Round 3
// baseline (454.834 us; speedup 1.0000x reference)
//
#include <hip/hip_runtime.h>
#include <stdint.h>

#define HH   160
#define WW   576
#define CIN  64
#define BATCH 8
#define MAXD 48

typedef unsigned int  uint;
typedef unsigned short ushort;
typedef __attribute__((ext_vector_type(8))) short bf16x8;
typedef __attribute__((ext_vector_type(4))) float f32x4;

// ---------------- workspace layout (bytes) ----------------
static constexpr size_t WTA_OFF  = 0;        // ushort[32*9*64] BN-folded conv w, [ch][tap][ci]
static constexpr size_t DWT_OFF  = 36864;    // ushort[32*32] desc w, k-permuted
static constexpr size_t B1_OFF   = 38912;    // float[32] BN bias
static constexpr size_t B2_OFF   = 39040;    // float[32] desc bias
static constexpr size_t FEAT_OFF = 40960;    // bf16 NHWC features, L then R
static constexpr size_t FEAT_ELEMS = (size_t)BATCH * HH * WW * 32;

__device__ __forceinline__ uint f2bf(float f) {
    uint u = __float_as_uint(f);
    u = (u + 0x7fffu + ((u >> 16) & 1u)) >> 16;   // RNE
    return u;
}
__device__ __forceinline__ float bf2f_lo(uint u) { return __uint_as_float(u << 16); }
__device__ __forceinline__ float bf2f_hi(uint u) { return __uint_as_float(u & 0xffff0000u); }

// ---------------- kernel 0: fold BN, build bf16 weight layouts ----------------
__global__ void prep_kernel(const float* __restrict__ conv_w,
                            const float* __restrict__ gamma,
                            const float* __restrict__ beta,
                            const float* __restrict__ mean,
                            const float* __restrict__ var,
                            const float* __restrict__ desc_w,
                            const float* __restrict__ desc_b,
                            char* __restrict__ ws) {
    int tid = blockIdx.x * 256 + threadIdx.x;
    ushort* wtA = (ushort*)(ws + WTA_OFF);
    ushort* dwt = (ushort*)(ws + DWT_OFF);
    float*  b1  = (float*)(ws + B1_OFF);
    float*  b2  = (float*)(ws + B2_OFF);
    if (tid < 32 * 9 * 64) {               // WtA[(ch*9+tap)*64+ci]
        int ci = tid & 63;
        int r2 = tid >> 6;
        int tap = r2 % 9;
        int ch  = r2 / 9;
        float inv = gamma[ch] * rsqrtf(var[ch] + 1e-5f);
        wtA[tid] = (ushort)f2bf(conv_w[(size_t)(ch * 64 + ci) * 9 + tap] * inv);
    }
    if (tid < 1024) {                      // DwtP[o][p]: p=8g+j holds desc_w[o][4g+(j&3)+16*(j>>2)]
        int o = tid >> 5, p = tid & 31;
        int g = p >> 3, j = p & 7;
        int mid = 4 * g + (j & 3) + 16 * ((j >> 2) & 1);
        dwt[tid] = (ushort)f2bf(desc_w[o * 32 + mid]);
    }
    if (tid < 32) {
        float inv = gamma[tid] * rsqrtf(var[tid] + 1e-5f);
        b1[tid] = beta[tid] - mean[tid] * inv;
        b2[tid] = desc_b[tid];
    }
}

// ---------------- kernel 1: MFMA conv3x3 + BN + ReLU + 1x1 ----------------
// Block: 512 thr (8 waves) -> 8 output rows x 32 cols. Stage 10x34 pixels x 64ci
// bf16 in LDS, XOR-swizzled: physical octet slot p of pixel lin holds logical
// ci-octet (p ^ (lin&7)). All b128 LDS ops bank-balanced.
#define NXB (WW / 32)     // 18
#define NYB (HH / 8)      // 20
#define NWG (NXB * NYB * 2 * BATCH)   // 5760 = 8 * 720
__global__ __launch_bounds__(512, 6)
void feat_mfma(const float* __restrict__ left,
               const float* __restrict__ right,
               const char* __restrict__ ws,
               ushort* __restrict__ featL,
               ushort* __restrict__ featR) {
    __shared__ __align__(16) ushort tile[10 * 34 * 64];   // 43,520 B -> 3 blocks/CU

    // bijective XCD swizzle: 5760 = 8*720; each XCD gets 2 whole images,
    // x-fastest then row order -> halo rows/cols are L2-resident.
    int bid = blockIdx.x;
    int nid = (bid & 7) * (NWG / 8) + (bid >> 3);
    int x    = nid % NXB;
    int rest = nid / NXB;
    int hy   = rest % NYB;
    int z    = rest / NYB;                  // 0..7 left, 8..15 right
    int b    = z & 7;
    const float* __restrict__ in = (z < 8 ? left : right) + (size_t)b * CIN * HH * WW;
    ushort* __restrict__ feat = (z < 8 ? featL : featR);
    const int w0 = x * 32;
    const int h0 = hy * 8;
    const int PL = HH * WW;

    // ---- stage input tile (f32 NCHW -> bf16 swizzled LDS) ----
    for (int t = threadIdx.x; t < 10 * 34 * 8; t += 512) {
        int octP = t & 7;                   // physical 16B slot within pixel
        int lin  = t >> 3;                  // r*34 + c
        int r = lin / 34;
        int c = lin - r * 34;
        int gh = h0 + r - 1;
        int gw = w0 + c - 1;
        uint4 pk = make_uint4(0u, 0u, 0u, 0u);
        if ((unsigned)gh < HH && (unsigned)gw < WW) {
            int oct = octP ^ (lin & 7);     // logical ci-octet for this slot
            const float* src = in + (size_t)(oct * 8) * PL + gh * WW + gw;
            float f0 = src[0];
            float f1 = src[(size_t)PL];
            float f2 = src[(size_t)2 * PL];
            float f3 = src[(size_t)3 * PL];
            float f4 = src[(size_t)4 * PL];
            float f5 = src[(size_t)5 * PL];
            float f6 = src[(size_t)6 * PL];
            float f7 = src[(size_t)7 * PL];
            pk.x = f2bf(f0) | (f2bf(f1) << 16);
            pk.y = f2bf(f2) | (f2bf(f3) << 16);
            pk.z = f2bf(f4) | (f2bf(f5) << 16);
            pk.w = f2bf(f6) | (f2bf(f7) << 16);
        }
        *(uint4*)&tile[lin * 64 + octP * 8] = pk;
    }
    __syncthreads();

    const int lane = threadIdx.x & 63;
    const int wv   = threadIdx.x >> 6;       // 0..7 -> output row h0+wv
    const int ln   = lane & 15;              // pixel within n-tile / ch row
    const int g    = lane >> 4;              // k-group 0..3

    const ushort* __restrict__ wtA = (const ushort*)(ws + WTA_OFF);
    const ushort* aBase = wtA + ln * 576 + g * 8;

    f32x4 acc[2][2] = {};                    // [mt(ch16)][nt(pix16)]

#pragma unroll
    for (int tap = 0; tap < 9; ++tap) {
        const int r = tap / 3, kw = tap % 3;
        bf16x8 a0k0 = *(const bf16x8*)(aBase + tap * 64);
        bf16x8 a0k1 = *(const bf16x8*)(aBase + tap * 64 + 32);
        bf16x8 a1k0 = *(const bf16x8*)(aBase + 9216 + tap * 64);
        bf16x8 a1k1 = *(const bf16x8*)(aBase + 9216 + tap * 64 + 32);
#pragma unroll
        for (int kk = 0; kk < 2; ++kk) {
            bf16x8 bb[2];
#pragma unroll
            for (int nt = 0; nt < 2; ++nt) {
                int lin = (wv + r) * 34 + nt * 16 + ln + kw;
                int oct = (kk * 4 + g) ^ (lin & 7);
                bb[nt] = *(const bf16x8*)&tile[lin * 64 + oct * 8];
            }
            bf16x8 a0 = kk ? a0k1 : a0k0;
            bf16x8 a1 = kk ? a1k1 : a1k0;
            acc[0][0] = __builtin_amdgcn_mfma_f32_16x16x32_bf16(a0, bb[0], acc[0][0], 0, 0, 0);
            acc[0][1] = __builtin_amdgcn_mfma_f32_16x16x32_bf16(a0, bb[1], acc[0][1], 0, 0, 0);
            acc[1][0] = __builtin_amdgcn_mfma_f32_16x16x32_bf16(a1, bb[0], acc[1][0], 0, 0, 0);
            acc[1][1] = __builtin_amdgcn_mfma_f32_16x16x32_bf16(a1, bb[1], acc[1][1], 0, 0, 0);
        }
    }

    // ---- BN bias + ReLU, pack P-fragments in C-layout order ----
    const float* __restrict__ b1 = (const float*)(ws + B1_OFF);
    const float* __restrict__ b2 = (const float*)(ws + B2_OFF);
    f32x4 b1v0 = *(const f32x4*)(b1 + g * 4);
    f32x4 b1v1 = *(const f32x4*)(b1 + 16 + g * 4);
    bf16x8 p[2];
#pragma unroll
    for (int nt = 0; nt < 2; ++nt) {
#pragma unroll
        for (int j = 0; j < 8; ++j) {
            float v = acc[j >> 2][nt][j & 3] + ((j >> 2) ? b1v1[j & 3] : b1v0[j & 3]);
            v = fmaxf(v, 0.f);
            p[nt][j] = (short)f2bf(v);
        }
    }

    // ---- 1x1 desc conv (k-permuted weights), bias-initialized acc ----
    const ushort* __restrict__ dwt = (const ushort*)(ws + DWT_OFF);
    const ushort* dBase = dwt + ln * 32 + g * 8;
    bf16x8 da0 = *(const bf16x8*)(dBase);
    bf16x8 da1 = *(const bf16x8*)(dBase + 512);
    f32x4 b2v0 = *(const f32x4*)(b2 + g * 4);
    f32x4 b2v1 = *(const f32x4*)(b2 + 16 + g * 4);
    f32x4 acc2[2][2];
#pragma unroll
    for (int nt = 0; nt < 2; ++nt) { acc2[0][nt] = b2v0; acc2[1][nt] = b2v1; }
#pragma unroll
    for (int nt = 0; nt < 2; ++nt) {
        acc2[0][nt] = __builtin_amdgcn_mfma_f32_16x16x32_bf16(da0, p[nt], acc2[0][nt], 0, 0, 0);
        acc2[1][nt] = __builtin_amdgcn_mfma_f32_16x16x32_bf16(da1, p[nt], acc2[1][nt], 0, 0, 0);
    }

    // ---- store features bf16 NHWC: ch = 16*mt2 + 4g + reg ----
    size_t pixBase = ((size_t)b * HH + h0 + wv) * WW + w0 + ln;
#pragma unroll
    for (int nt = 0; nt < 2; ++nt) {
#pragma unroll
        for (int mt2 = 0; mt2 < 2; ++mt2) {
            uint u0 = f2bf(acc2[mt2][nt][0]) | (f2bf(acc2[mt2][nt][1]) << 16);
            uint u1 = f2bf(acc2[mt2][nt][2]) | (f2bf(acc2[mt2][nt][3]) << 16);
            *(uint2*)(feat + (pixBase + nt * 16) * 32 + mt2 * 16 + g * 4) = make_uint2(u0, u1);
        }
    }
}

// ---------------- kernel 2: 48-disparity correlation cost volume ----------------
#define CVT 192
__global__ __launch_bounds__(CVT)
void cv_kernel(const ushort* __restrict__ featL,
               const ushort* __restrict__ featR,
               float* __restrict__ out) {
    // R row staged with 80 B stride per pixel: 80*l mod 128 covers all eight
    // 16B slots -> bank-balanced ds_read_b128 at lane-stride-1 w.
    __shared__ ushort r_lds[WW * 40];           // 46,080 B

    const int t  = threadIdx.x;                 // 0..191
    const int bh = blockIdx.x;                  // b*160 + h
    const int b  = bh / HH;
    const int h  = bh - b * HH;
    const ushort* __restrict__ Lrow = featL + ((size_t)b * HH + h) * WW * 32;
    const ushort* __restrict__ Rrow = featR + ((size_t)b * HH + h) * WW * 32;

#pragma unroll
    for (int k = 0; k < 3; ++k) {
        int w = t + k * CVT;
        const uint4* src = (const uint4*)(Rrow + (size_t)w * 32);
        uint4* dst = (uint4*)(r_lds + (size_t)w * 40);
#pragma unroll
        for (int j = 0; j < 4; ++j) dst[j] = src[j];
    }

    float Lf[3][32];
#pragma unroll
    for (int k = 0; k < 3; ++k) {
        int w = t + k * CVT;
        const uint4* src = (const uint4*)(Lrow + (size_t)w * 32);
#pragma unroll
        for (int j = 0; j < 4; ++j) {
            uint4 v = src[j];
            uint vv[4] = {v.x, v.y, v.z, v.w};
#pragma unroll
            for (int q = 0; q < 4; ++q) {
                Lf[k][j * 8 + q * 2]     = bf2f_lo(vv[q]);
                Lf[k][j * 8 + q * 2 + 1] = bf2f_hi(vv[q]);
            }
        }
    }
    __syncthreads();

    float* __restrict__ outBase = out + ((size_t)b * MAXD * HH + h) * WW;
    for (int d = 0; d < MAXD; ++d) {
#pragma unroll
        for (int k = 0; k < 3; ++k) {
            int w = t + k * CVT;
            float res = 0.f;
            if (w >= d) {
                const uint4* rp = (const uint4*)(r_lds + (size_t)(w - d) * 40);
                float s0 = 0.f, s1 = 0.f;
#pragma unroll
                for (int j = 0; j < 4; ++j) {
                    uint4 v = rp[j];
                    uint vv[4] = {v.x, v.y, v.z, v.w};
#pragma unroll
                    for (int q = 0; q < 4; ++q) {
                        int idx = j * 8 + q * 2;
                        s0 = fmaf(Lf[k][idx],     bf2f_lo(vv[q]), s0);
                        s1 = fmaf(Lf[k][idx + 1], bf2f_hi(vv[q]), s1);
                    }
                }
                res = (s0 + s1) * (1.f / 32.f);
            }
            outBase[(size_t)d * HH * WW + w] = res;
        }
    }
}

// ---------------- launch ----------------
extern "C" void kernel_launch(void* const* d_in, const int* in_sizes, int n_in,
                              void* d_out, int out_size, void* d_ws, size_t ws_size,
                              hipStream_t stream) {
    const float* left   = (const float*)d_in[0];
    const float* right  = (const float*)d_in[1];
    const float* conv_w = (const float*)d_in[2];
    const float* gamma  = (const float*)d_in[3];
    const float* beta   = (const float*)d_in[4];
    const float* mean   = (const float*)d_in[5];
    const float* var    = (const float*)d_in[6];
    const float* desc_w = (const float*)d_in[7];
    const float* desc_b = (const float*)d_in[8];
    float*  out   = (float*)d_out;
    char*   ws    = (char*)d_ws;
    ushort* featL = (ushort*)(ws + FEAT_OFF);
    ushort* featR = featL + FEAT_ELEMS;

    prep_kernel<<<72, 256, 0, stream>>>(conv_w, gamma, beta, mean, var, desc_w, desc_b, ws);
    feat_mfma<<<NWG, 512, 0, stream>>>(left, right, ws, featL, featR);
    cv_kernel<<<BATCH * HH, CVT, 0, stream>>>(featL, featR, out);
}

// Round 4
// 254.102 us; speedup vs baseline: 1.7900x; 1.7900x over previous
//
#include <hip/hip_runtime.h>
#include <stdint.h>

#define HH   160
#define WW   576
#define CIN  64
#define BATCH 8
#define MAXD 48

typedef unsigned int  uint;
typedef unsigned short ushort;
typedef __attribute__((ext_vector_type(8))) short bf16x8;
typedef __attribute__((ext_vector_type(4))) float f32x4;

// ---------------- workspace layout (bytes) ----------------
// wtB : ushort[36*64*8] @ 0      fragment-major conv weights:
//       frag f=(tap*2+kk)*2+mt, lane l=g*16+ln, elem j
//       = foldedW[ch=mt*16+ln][ci=kk*32+g*8+j][tap]   (36 KB)
// dwt : ushort[32*32]  @ 36864   desc w, k-permuted to C-frag order
// b1  : float[32]      @ 38912   BN bias
// b2  : float[32]      @ 39040   desc bias
// feat: bf16 NHWC features @ 40960, L then R
static constexpr size_t WTB_OFF  = 0;
static constexpr size_t DWT_OFF  = 36864;
static constexpr size_t B1_OFF   = 38912;
static constexpr size_t B2_OFF   = 39040;
static constexpr size_t FEAT_OFF = 40960;
static constexpr size_t FEAT_ELEMS = (size_t)BATCH * HH * WW * 32;

__device__ __forceinline__ uint f2bf(float f) {
    uint u = __float_as_uint(f);
    u = (u + 0x7fffu + ((u >> 16) & 1u)) >> 16;   // RNE
    return u;
}
__device__ __forceinline__ float bf2f_lo(uint u) { return __uint_as_float(u << 16); }
__device__ __forceinline__ float bf2f_hi(uint u) { return __uint_as_float(u & 0xffff0000u); }
__device__ __forceinline__ uint pk2(float a, float b) { return f2bf(a) | (f2bf(b) << 16); }

// ---------------- kernel 0: fold BN, build weight layouts ----------------
__global__ void prep_kernel(const float* __restrict__ conv_w,
                            const float* __restrict__ gamma,
                            const float* __restrict__ beta,
                            const float* __restrict__ mean,
                            const float* __restrict__ var,
                            const float* __restrict__ desc_w,
                            const float* __restrict__ desc_b,
                            char* __restrict__ ws) {
    int tid = blockIdx.x * 256 + threadIdx.x;
    ushort* wtB = (ushort*)(ws + WTB_OFF);
    ushort* dwt = (ushort*)(ws + DWT_OFF);
    float*  b1  = (float*)(ws + B1_OFF);
    float*  b2  = (float*)(ws + B2_OFF);
    if (tid < 36 * 64 * 8) {               // fragment-major conv weights
        int j    = tid & 7;
        int lane = (tid >> 3) & 63;
        int frag = tid >> 9;               // 0..35
        int ln = lane & 15, g = lane >> 4;
        int mt  = frag & 1;
        int kk  = (frag >> 1) & 1;
        int tap = frag >> 2;               // 0..8
        int ch = mt * 16 + ln;
        int ci = kk * 32 + g * 8 + j;
        float inv = gamma[ch] * rsqrtf(var[ch] + 1e-5f);
        wtB[tid] = (ushort)f2bf(conv_w[(size_t)(ch * 64 + ci) * 9 + tap] * inv);
    }
    if (tid < 1024) {                      // dwt[o][p]: p=8g+j holds desc_w[o][4g+(j&3)+16*(j>>2)]
        int o = tid >> 5, p = tid & 31;
        int g = p >> 3, j = p & 7;
        int mid = 4 * g + (j & 3) + 16 * ((j >> 2) & 1);
        dwt[tid] = (ushort)f2bf(desc_w[o * 32 + mid]);
    }
    if (tid < 32) {
        float inv = gamma[tid] * rsqrtf(var[tid] + 1e-5f);
        b1[tid] = beta[tid] - mean[tid] * inv;
        b2[tid] = desc_b[tid];
    }
}

// ---------------- kernel 1: MFMA conv3x3 + BN + ReLU + 1x1 ----------------
// Block: 512 thr, out-tile 4 rows x 64 cols. In-tile [6 rows][72 cols][64 ci]
// bf16 in LDS (55.3 KB, 2 blocks/CU). Staging: each task reads 8 aligned
// float4 (4 w x 8 ci planes, fully coalesced), register-transposes, writes
// ds_write_b128 with oct-XOR swizzle (phys oct = oct ^ (px&7)) -> conflict-free.
#define NXB 9      // 576/64
#define NYB 40     // 160/4
#define NWG (NXB * NYB * 2 * BATCH)   // 5760 = 8 * 720
__global__ __launch_bounds__(512, 4)
void feat_mfma(const float* __restrict__ left,
               const float* __restrict__ right,
               const char* __restrict__ ws,
               ushort* __restrict__ featL,
               ushort* __restrict__ featR) {
    __shared__ __align__(16) ushort tile[6 * 72 * 64];   // 55,296 B

    // bijective XCD swizzle: 5760 = 8*720; x-fastest then row order
    int bid = blockIdx.x;
    int nid = (bid & 7) * (NWG / 8) + (bid >> 3);
    int x    = nid % NXB;
    int rest = nid / NXB;
    int hy   = rest % NYB;
    int z    = rest / NYB;                  // 0..7 left, 8..15 right
    int b    = z & 7;
    const float* __restrict__ in = (z < 8 ? left : right) + (size_t)b * CIN * HH * WW;
    ushort* __restrict__ feat = (z < 8 ? featL : featR);
    const int w0 = x * 64;
    const int h0 = hy * 4;
    const int PL = HH * WW;

    // ---- stage input tile: 864 tasks (r, oct, g) ----
    for (int t = threadIdx.x; t < 6 * 8 * 18; t += 512) {
        int g    = t % 18;                   // w4-group 0..17
        int rest2 = t / 18;
        int oct  = rest2 & 7;                // ci octet 0..7
        int r    = rest2 >> 3;               // row 0..5
        int gh  = h0 + r - 1;
        int gw4 = w0 - 4 + g * 4;            // 16B-aligned global col base
        float4 v[8];
        if (((unsigned)gh < HH) && ((unsigned)gw4 < WW)) {
            const float* src = in + (size_t)(oct * 8) * PL + (size_t)gh * WW + gw4;
#pragma unroll
            for (int j = 0; j < 8; ++j)
                v[j] = *(const float4*)(src + (size_t)j * PL);
        } else {
#pragma unroll
            for (int j = 0; j < 8; ++j) v[j] = make_float4(0.f, 0.f, 0.f, 0.f);
        }
#pragma unroll
        for (int k = 0; k < 4; ++k) {
            float w_[8] = {k == 0 ? v[0].x : k == 1 ? v[0].y : k == 2 ? v[0].z : v[0].w,
                           k == 0 ? v[1].x : k == 1 ? v[1].y : k == 2 ? v[1].z : v[1].w,
                           k == 0 ? v[2].x : k == 1 ? v[2].y : k == 2 ? v[2].z : v[2].w,
                           k == 0 ? v[3].x : k == 1 ? v[3].y : k == 2 ? v[3].z : v[3].w,
                           k == 0 ? v[4].x : k == 1 ? v[4].y : k == 2 ? v[4].z : v[4].w,
                           k == 0 ? v[5].x : k == 1 ? v[5].y : k == 2 ? v[5].z : v[5].w,
                           k == 0 ? v[6].x : k == 1 ? v[6].y : k == 2 ? v[6].z : v[6].w,
                           k == 0 ? v[7].x : k == 1 ? v[7].y : k == 2 ? v[7].z : v[7].w};
            uint4 o;
            o.x = pk2(w_[0], w_[1]);
            o.y = pk2(w_[2], w_[3]);
            o.z = pk2(w_[4], w_[5]);
            o.w = pk2(w_[6], w_[7]);
            int px = r * 72 + g * 4 + k;
            *(uint4*)&tile[(size_t)px * 64 + ((oct ^ (px & 7)) * 8)] = o;
        }
    }
    __syncthreads();

    const int lane = threadIdx.x & 63;
    const int wv   = threadIdx.x >> 6;       // 0..7
    const int ln   = lane & 15;
    const int g    = lane >> 4;
    const int orow = wv >> 1;                // out row 0..3
    const int ocol = (wv & 1) * 32;          // out col half

    const ushort* __restrict__ wtB = (const ushort*)(ws + WTB_OFF);

    f32x4 acc[2][2] = {};                    // [mt(ch16)][nt(pix16)]

#pragma unroll
    for (int tap = 0; tap < 9; ++tap) {
        const int r = tap / 3, kw = tap % 3;
#pragma unroll
        for (int kk = 0; kk < 2; ++kk) {
            bf16x8 a0 = *(const bf16x8*)(wtB + (size_t)((tap * 2 + kk) * 2 + 0) * 512 + lane * 8);
            bf16x8 a1 = *(const bf16x8*)(wtB + (size_t)((tap * 2 + kk) * 2 + 1) * 512 + lane * 8);
            bf16x8 bb[2];
#pragma unroll
            for (int nt = 0; nt < 2; ++nt) {
                int px = (orow + r) * 72 + ocol + nt * 16 + ln + kw + 3;
                bb[nt] = *(const bf16x8*)&tile[(size_t)px * 64 + (((kk * 4 + g) ^ (px & 7)) * 8)];
            }
            acc[0][0] = __builtin_amdgcn_mfma_f32_16x16x32_bf16(a0, bb[0], acc[0][0], 0, 0, 0);
            acc[0][1] = __builtin_amdgcn_mfma_f32_16x16x32_bf16(a0, bb[1], acc[0][1], 0, 0, 0);
            acc[1][0] = __builtin_amdgcn_mfma_f32_16x16x32_bf16(a1, bb[0], acc[1][0], 0, 0, 0);
            acc[1][1] = __builtin_amdgcn_mfma_f32_16x16x32_bf16(a1, bb[1], acc[1][1], 0, 0, 0);
        }
    }

    // ---- BN bias + ReLU, pack P-fragments in C-layout order ----
    const float* __restrict__ b1 = (const float*)(ws + B1_OFF);
    const float* __restrict__ b2 = (const float*)(ws + B2_OFF);
    f32x4 b1v0 = *(const f32x4*)(b1 + g * 4);
    f32x4 b1v1 = *(const f32x4*)(b1 + 16 + g * 4);
    bf16x8 p[2];
#pragma unroll
    for (int nt = 0; nt < 2; ++nt) {
#pragma unroll
        for (int j = 0; j < 8; ++j) {
            float v = acc[j >> 2][nt][j & 3] + ((j >> 2) ? b1v1[j & 3] : b1v0[j & 3]);
            v = fmaxf(v, 0.f);
            p[nt][j] = (short)f2bf(v);
        }
    }

    // ---- 1x1 desc conv (k-permuted weights), bias-initialized acc ----
    const ushort* __restrict__ dwt = (const ushort*)(ws + DWT_OFF);
    const ushort* dBase = dwt + ln * 32 + g * 8;
    bf16x8 da0 = *(const bf16x8*)(dBase);
    bf16x8 da1 = *(const bf16x8*)(dBase + 512);
    f32x4 b2v0 = *(const f32x4*)(b2 + g * 4);
    f32x4 b2v1 = *(const f32x4*)(b2 + 16 + g * 4);
    f32x4 acc2[2][2];
#pragma unroll
    for (int nt = 0; nt < 2; ++nt) { acc2[0][nt] = b2v0; acc2[1][nt] = b2v1; }
#pragma unroll
    for (int nt = 0; nt < 2; ++nt) {
        acc2[0][nt] = __builtin_amdgcn_mfma_f32_16x16x32_bf16(da0, p[nt], acc2[0][nt], 0, 0, 0);
        acc2[1][nt] = __builtin_amdgcn_mfma_f32_16x16x32_bf16(da1, p[nt], acc2[1][nt], 0, 0, 0);
    }

    // ---- store features bf16 NHWC: ch = 16*mt2 + 4g + reg ----
    size_t pixBase = ((size_t)b * HH + h0 + orow) * WW + w0 + ocol + ln;
#pragma unroll
    for (int nt = 0; nt < 2; ++nt) {
#pragma unroll
        for (int mt2 = 0; mt2 < 2; ++mt2) {
            uint u0 = f2bf(acc2[mt2][nt][0]) | (f2bf(acc2[mt2][nt][1]) << 16);
            uint u1 = f2bf(acc2[mt2][nt][2]) | (f2bf(acc2[mt2][nt][3]) << 16);
            *(uint2*)(feat + (pixBase + nt * 16) * 32 + mt2 * 16 + g * 4) = make_uint2(u0, u1);
        }
    }
}

// ---------------- kernel 2: 48-disparity correlation cost volume ----------------
#define CVT 192
__global__ __launch_bounds__(CVT)
void cv_kernel(const ushort* __restrict__ featL,
               const ushort* __restrict__ featR,
               float* __restrict__ out) {
    // R row staged with 80 B stride per pixel: 80*l mod 128 covers all eight
    // 16B slots -> bank-balanced ds_read_b128 at lane-stride-1 w.
    __shared__ ushort r_lds[WW * 40];           // 46,080 B

    const int t  = threadIdx.x;                 // 0..191
    const int bh = blockIdx.x;                  // b*160 + h
    const int b  = bh / HH;
    const int h  = bh - b * HH;
    const ushort* __restrict__ Lrow = featL + ((size_t)b * HH + h) * WW * 32;
    const ushort* __restrict__ Rrow = featR + ((size_t)b * HH + h) * WW * 32;

#pragma unroll
    for (int k = 0; k < 3; ++k) {
        int w = t + k * CVT;
        const uint4* src = (const uint4*)(Rrow + (size_t)w * 32);
        uint4* dst = (uint4*)(r_lds + (size_t)w * 40);
#pragma unroll
        for (int j = 0; j < 4; ++j) dst[j] = src[j];
    }

    float Lf[3][32];
#pragma unroll
    for (int k = 0; k < 3; ++k) {
        int w = t + k * CVT;
        const uint4* src = (const uint4*)(Lrow + (size_t)w * 32);
#pragma unroll
        for (int j = 0; j < 4; ++j) {
            uint4 v = src[j];
            uint vv[4] = {v.x, v.y, v.z, v.w};
#pragma unroll
            for (int q = 0; q < 4; ++q) {
                Lf[k][j * 8 + q * 2]     = bf2f_lo(vv[q]);
                Lf[k][j * 8 + q * 2 + 1] = bf2f_hi(vv[q]);
            }
        }
    }
    __syncthreads();

    float* __restrict__ outBase = out + ((size_t)b * MAXD * HH + h) * WW;
    for (int d = 0; d < MAXD; ++d) {
#pragma unroll
        for (int k = 0; k < 3; ++k) {
            int w = t + k * CVT;
            float res = 0.f;
            if (w >= d) {
                const uint4* rp = (const uint4*)(r_lds + (size_t)(w - d) * 40);
                float s0 = 0.f, s1 = 0.f;
#pragma unroll
                for (int j = 0; j < 4; ++j) {
                    uint4 v = rp[j];
                    uint vv[4] = {v.x, v.y, v.z, v.w};
#pragma unroll
                    for (int q = 0; q < 4; ++q) {
                        int idx = j * 8 + q * 2;
                        s0 = fmaf(Lf[k][idx],     bf2f_lo(vv[q]), s0);
                        s1 = fmaf(Lf[k][idx + 1], bf2f_hi(vv[q]), s1);
                    }
                }
                res = (s0 + s1) * (1.f / 32.f);
            }
            outBase[(size_t)d * HH * WW + w] = res;
        }
    }
}

// ---------------- launch ----------------
extern "C" void kernel_launch(void* const* d_in, const int* in_sizes, int n_in,
                              void* d_out, int out_size, void* d_ws, size_t ws_size,
                              hipStream_t stream) {
    const float* left   = (const float*)d_in[0];
    const float* right  = (const float*)d_in[1];
    const float* conv_w = (const float*)d_in[2];
    const float* gamma  = (const float*)d_in[3];
    const float* beta   = (const float*)d_in[4];
    const float* mean   = (const float*)d_in[5];
    const float* var    = (const float*)d_in[6];
    const float* desc_w = (const float*)d_in[7];
    const float* desc_b = (const float*)d_in[8];
    float*  out   = (float*)d_out;
    char*   ws    = (char*)d_ws;
    ushort* featL = (ushort*)(ws + FEAT_OFF);
    ushort* featR = featL + FEAT_ELEMS;

    prep_kernel<<<72, 256, 0, stream>>>(conv_w, gamma, beta, mean, var, desc_w, desc_b, ws);
    feat_mfma<<<NWG, 512, 0, stream>>>(left, right, ws, featL, featR);
    cv_kernel<<<BATCH * HH, CVT, 0, stream>>>(featL, featR, out);
}